// Round 2
// baseline (3893.134 us; speedup 1.0000x reference)
//
#include <hip/hip_runtime.h>

#define D 128
#define EDIM 64
#define NODE_F 32
#define EDGE_F 16
#define B_PAIRS 256
#define MAXN 64
#define PROP_STEPS 3

#define MT 32     // edges per block in msg kernel
#define MTU 32    // nodes per block in update kernel
#define MTA 32    // rows per block in attfeat kernel
#define KC 16     // k-panel size for LDS-staged weights

// ---------------- encoders ----------------
__global__ __launch_bounds__(256) void encode_nodes(
    const float* __restrict__ nf, const float* __restrict__ W,
    const float* __restrict__ bias, float* __restrict__ h, int N)
{
  int t = threadIdx.x;
  int n = blockIdx.x * 2 + (t >> 7);
  int c = t & 127;
  if (n >= N) return;
  float acc = bias[c];
  #pragma unroll
  for (int k = 0; k < NODE_F; k++)
    acc += nf[(size_t)n * NODE_F + k] * W[k * D + c];
  h[(size_t)n * D + c] = acc;
}

__global__ __launch_bounds__(256) void encode_edges(
    const float* __restrict__ ef, const float* __restrict__ W,
    const float* __restrict__ bias, float* __restrict__ e, int E)
{
  int t = threadIdx.x;
  int eid = blockIdx.x * 4 + (t >> 6);
  int c = t & 63;
  if (eid >= E) return;
  float acc = bias[c];
  #pragma unroll
  for (int k = 0; k < EDGE_F; k++)
    acc += ef[(size_t)eid * EDGE_F + k] * W[k * EDIM + c];
  e[(size_t)eid * EDIM + c] = acc;
}

// ---------------- message + aggregate (the heavy kernel) ----------------
// edge_in = [h[from] | h[to] | e]  (320)
// msg = relu(edge_in @ W1 + b1) @ W2 + b2   (256)
// agg[to] += msg  (atomics)
__global__ __launch_bounds__(256, 2) void msg_kernel(
    const float* __restrict__ h, const float* __restrict__ ef,
    const int* __restrict__ from_idx, const int* __restrict__ to_idx,
    const float* __restrict__ W1, const float* __restrict__ b1,
    const float* __restrict__ W2, const float* __restrict__ b2,
    float* __restrict__ agg, int E)
{
  __shared__ float sA[MT * 320];   // 40KB: edge_in, later reused for hidden [MT*256]
  __shared__ float sW[KC * 256];   // 16KB

  int t = threadIdx.x;
  int wv = t >> 6, ln = t & 63;
  int e0 = blockIdx.x * MT;

  // stage edge_in rows [MT][320] (coalesced float4 within segments)
  for (int i = t * 4; i < MT * 320; i += 1024) {
    int r = i / 320, c = i - r * 320;
    int eid = e0 + r;
    float4 v = {0.f, 0.f, 0.f, 0.f};
    if (eid < E) {
      if (c < 128)      v = *(const float4*)(h  + (size_t)from_idx[eid] * D + c);
      else if (c < 256) v = *(const float4*)(h  + (size_t)to_idx[eid]  * D + (c - 128));
      else              v = *(const float4*)(ef + (size_t)eid * EDIM + (c - 256));
    }
    *(float4*)(sA + i) = v;
  }

  // ---- GEMM1: hidden[32][256] = relu(edge_in @ W1 + b1)
  float4 bb = *(const float4*)(b1 + ln * 4);
  float acc[8][4];
  #pragma unroll
  for (int j = 0; j < 8; j++) { acc[j][0] = bb.x; acc[j][1] = bb.y; acc[j][2] = bb.z; acc[j][3] = bb.w; }

  for (int kc = 0; kc < 320; kc += KC) {
    __syncthreads();
    for (int i = t * 4; i < KC * 256; i += 1024) {
      int kk = i >> 8, c = i & 255;
      *(float4*)(sW + i) = *(const float4*)(W1 + (size_t)(kc + kk) * 256 + c);
    }
    __syncthreads();
    #pragma unroll
    for (int k4 = 0; k4 < KC; k4 += 4) {
      float4 a[8];
      #pragma unroll
      for (int j = 0; j < 8; j++)
        a[j] = *(const float4*)(sA + (wv * 8 + j) * 320 + kc + k4);  // same-addr broadcast per wave
      #pragma unroll
      for (int k2 = 0; k2 < 4; k2++) {
        float4 w = *(const float4*)(sW + (k4 + k2) * 256 + ln * 4);
        #pragma unroll
        for (int j = 0; j < 8; j++) {
          float av = (k2 == 0) ? a[j].x : (k2 == 1) ? a[j].y : (k2 == 2) ? a[j].z : a[j].w;
          acc[j][0] += av * w.x; acc[j][1] += av * w.y;
          acc[j][2] += av * w.z; acc[j][3] += av * w.w;
        }
      }
    }
  }

  // relu + write hidden into sA (edge_in dead)
  __syncthreads();
  #pragma unroll
  for (int j = 0; j < 8; j++) {
    float4 v = { fmaxf(acc[j][0], 0.f), fmaxf(acc[j][1], 0.f),
                 fmaxf(acc[j][2], 0.f), fmaxf(acc[j][3], 0.f) };
    *(float4*)(sA + (wv * 8 + j) * 256 + ln * 4) = v;
  }

  // ---- GEMM2: msg = hidden @ W2 + b2
  float4 bb2 = *(const float4*)(b2 + ln * 4);
  #pragma unroll
  for (int j = 0; j < 8; j++) { acc[j][0] = bb2.x; acc[j][1] = bb2.y; acc[j][2] = bb2.z; acc[j][3] = bb2.w; }

  for (int kc = 0; kc < 256; kc += KC) {
    __syncthreads();
    for (int i = t * 4; i < KC * 256; i += 1024) {
      int kk = i >> 8, c = i & 255;
      *(float4*)(sW + i) = *(const float4*)(W2 + (size_t)(kc + kk) * 256 + c);
    }
    __syncthreads();
    #pragma unroll
    for (int k4 = 0; k4 < KC; k4 += 4) {
      float4 a[8];
      #pragma unroll
      for (int j = 0; j < 8; j++)
        a[j] = *(const float4*)(sA + (wv * 8 + j) * 256 + kc + k4);
      #pragma unroll
      for (int k2 = 0; k2 < 4; k2++) {
        float4 w = *(const float4*)(sW + (k4 + k2) * 256 + ln * 4);
        #pragma unroll
        for (int j = 0; j < 8; j++) {
          float av = (k2 == 0) ? a[j].x : (k2 == 1) ? a[j].y : (k2 == 2) ? a[j].z : a[j].w;
          acc[j][0] += av * w.x; acc[j][1] += av * w.y;
          acc[j][2] += av * w.z; acc[j][3] += av * w.w;
        }
      }
    }
  }

  // segment-sum via atomics (coalesced across lanes)
  #pragma unroll
  for (int j = 0; j < 8; j++) {
    int eid = e0 + wv * 8 + j;
    if (eid < E) {
      float* dst = agg + (size_t)to_idx[eid] * 256 + ln * 4;
      unsafeAtomicAdd(dst + 0, acc[j][0]);
      unsafeAtomicAdd(dst + 1, acc[j][1]);
      unsafeAtomicAdd(dst + 2, acc[j][2]);
      unsafeAtomicAdd(dst + 3, acc[j][3]);
    }
  }
}

// ---------------- node update ----------------
// h += concat(h, agg) @ W_upd + b_upd
__global__ __launch_bounds__(256, 2) void update_kernel(
    float* __restrict__ h, const float* __restrict__ agg,
    const float* __restrict__ Wu, const float* __restrict__ bu, int N)
{
  __shared__ float sA[MTU * 384];  // 48KB
  __shared__ float sW[KC * 128];   // 8KB
  int t = threadIdx.x, wv = t >> 6, ln = t & 63;
  int n0 = blockIdx.x * MTU;

  for (int i = t * 4; i < MTU * 384; i += 1024) {
    int r = i / 384, c = i - r * 384;
    int n = n0 + r;
    float4 v = {0.f, 0.f, 0.f, 0.f};
    if (n < N) {
      if (c < 128) v = *(const float4*)(h   + (size_t)n * D + c);
      else         v = *(const float4*)(agg + (size_t)n * 256 + (c - 128));
    }
    *(float4*)(sA + i) = v;
  }

  float2 bb = *(const float2*)(bu + ln * 2);
  float acc[8][2];
  #pragma unroll
  for (int j = 0; j < 8; j++) { acc[j][0] = bb.x; acc[j][1] = bb.y; }

  for (int kc = 0; kc < 384; kc += KC) {
    __syncthreads();
    for (int i = t * 4; i < KC * 128; i += 1024) {
      int kk = i >> 7, c = i & 127;
      *(float4*)(sW + i) = *(const float4*)(Wu + (size_t)(kc + kk) * 128 + c);
    }
    __syncthreads();
    #pragma unroll
    for (int k4 = 0; k4 < KC; k4 += 4) {
      float4 a[8];
      #pragma unroll
      for (int j = 0; j < 8; j++)
        a[j] = *(const float4*)(sA + (wv * 8 + j) * 384 + kc + k4);
      #pragma unroll
      for (int k2 = 0; k2 < 4; k2++) {
        float2 w = *(const float2*)(sW + (k4 + k2) * 128 + ln * 2);
        #pragma unroll
        for (int j = 0; j < 8; j++) {
          float av = (k2 == 0) ? a[j].x : (k2 == 1) ? a[j].y : (k2 == 2) ? a[j].z : a[j].w;
          acc[j][0] += av * w.x; acc[j][1] += av * w.y;
        }
      }
    }
  }

  #pragma unroll
  for (int j = 0; j < 8; j++) {
    int n = n0 + wv * 8 + j;
    if (n < N) {
      float2* p = (float2*)(h + (size_t)n * D + ln * 2);
      float2 old = *p;
      float2 nv = { old.x + acc[j][0], old.y + acc[j][1] };
      *p = nv;
    }
  }
}

// ---------------- scatter into padded stacks ----------------
__global__ void scatter_kernel(const float* __restrict__ h, const int* __restrict__ pos,
                               float* __restrict__ flat, int N)
{
  int idx = blockIdx.x * 256 + threadIdx.x;
  if (idx >= N * D) return;
  int n = idx >> 7, c = idx & 127;
  flat[(size_t)pos[n] * D + c] = h[idx];
}

// ---------------- attention features ----------------
// t = (relu(x@Wa1+ba1)@Wa2+ba2) * mask
__global__ __launch_bounds__(256) void attfeat_kernel(
    const float* __restrict__ flat,
    const float* __restrict__ Wa1, const float* __restrict__ ba1,
    const float* __restrict__ Wa2, const float* __restrict__ ba2,
    const int* __restrict__ qsizes, const int* __restrict__ csizes,
    float* __restrict__ tf)
{
  __shared__ float sA[MTA * 128];  // 16KB (x, then hidden)
  __shared__ float sW[KC * 128];   // 8KB
  int t = threadIdx.x, wv = t >> 6, ln = t & 63;
  int r0 = blockIdx.x * MTA;

  for (int i = t * 4; i < MTA * 128; i += 1024)
    *(float4*)(sA + i) = *(const float4*)(flat + (size_t)r0 * 128 + i);

  float2 bb = *(const float2*)(ba1 + ln * 2);
  float acc[8][2];
  #pragma unroll
  for (int j = 0; j < 8; j++) { acc[j][0] = bb.x; acc[j][1] = bb.y; }

  for (int kc = 0; kc < 128; kc += KC) {
    __syncthreads();
    for (int i = t * 4; i < KC * 128; i += 1024) {
      int kk = i >> 7, c = i & 127;
      *(float4*)(sW + i) = *(const float4*)(Wa1 + (size_t)(kc + kk) * 128 + c);
    }
    __syncthreads();
    #pragma unroll
    for (int k4 = 0; k4 < KC; k4 += 4) {
      float4 a[8];
      #pragma unroll
      for (int j = 0; j < 8; j++)
        a[j] = *(const float4*)(sA + (wv * 8 + j) * 128 + kc + k4);
      #pragma unroll
      for (int k2 = 0; k2 < 4; k2++) {
        float2 w = *(const float2*)(sW + (k4 + k2) * 128 + ln * 2);
        #pragma unroll
        for (int j = 0; j < 8; j++) {
          float av = (k2 == 0) ? a[j].x : (k2 == 1) ? a[j].y : (k2 == 2) ? a[j].z : a[j].w;
          acc[j][0] += av * w.x; acc[j][1] += av * w.y;
        }
      }
    }
  }

  __syncthreads();
  #pragma unroll
  for (int j = 0; j < 8; j++) {
    sA[(wv * 8 + j) * 128 + ln * 2 + 0] = fmaxf(acc[j][0], 0.f);
    sA[(wv * 8 + j) * 128 + ln * 2 + 1] = fmaxf(acc[j][1], 0.f);
  }

  float2 bb2 = *(const float2*)(ba2 + ln * 2);
  #pragma unroll
  for (int j = 0; j < 8; j++) { acc[j][0] = bb2.x; acc[j][1] = bb2.y; }

  for (int kc = 0; kc < 128; kc += KC) {
    __syncthreads();
    for (int i = t * 4; i < KC * 128; i += 1024) {
      int kk = i >> 7, c = i & 127;
      *(float4*)(sW + i) = *(const float4*)(Wa2 + (size_t)(kc + kk) * 128 + c);
    }
    __syncthreads();
    #pragma unroll
    for (int k4 = 0; k4 < KC; k4 += 4) {
      float4 a[8];
      #pragma unroll
      for (int j = 0; j < 8; j++)
        a[j] = *(const float4*)(sA + (wv * 8 + j) * 128 + kc + k4);
      #pragma unroll
      for (int k2 = 0; k2 < 4; k2++) {
        float2 w = *(const float2*)(sW + (k4 + k2) * 128 + ln * 2);
        #pragma unroll
        for (int j = 0; j < 8; j++) {
          float av = (k2 == 0) ? a[j].x : (k2 == 1) ? a[j].y : (k2 == 2) ? a[j].z : a[j].w;
          acc[j][0] += av * w.x; acc[j][1] += av * w.y;
        }
      }
    }
  }

  #pragma unroll
  for (int j = 0; j < 8; j++) {
    int row = r0 + wv * 8 + j;
    int part = row >> 14, b = (row >> 6) & 255, pp = row & 63;
    int sz = part ? csizes[b] : qsizes[b];
    float m = (pp < sz) ? 1.f : 0.f;
    tf[(size_t)row * 128 + ln * 2 + 0] = acc[j][0] * m;
    tf[(size_t)row * 128 + ln * 2 + 1] = acc[j][1] * m;
  }
}

// ---------------- per-pair attention score ----------------
__global__ __launch_bounds__(256, 2) void score_kernel(
    const float* __restrict__ tf, const float* __restrict__ flat,
    const int* __restrict__ qsizes, const int* __restrict__ csizes,
    float* __restrict__ out)
{
  __shared__ float SL[64 * 65];   // logits (padded stride 65)
  __shared__ float SP[64 * 65];   // q_to_c
  __shared__ float SP2[64 * 65];  // c_to_q
  __shared__ float Atk[16 * 68];  // tq^T k-slice
  __shared__ float Btk[16 * 68];  // tc^T k-slice
  __shared__ float red[8];

  int b = blockIdx.x, t = threadIdx.x;
  const float* tq = tf + (size_t)b * 64 * 128;
  const float* tc = tf + ((size_t)16384 + (size_t)b * 64) * 128;
  const float* sq = flat + (size_t)b * 64 * 128;
  const float* sc = flat + ((size_t)16384 + (size_t)b * 64) * 128;
  int qs = qsizes[b], cs = csizes[b];

  int qg = (t >> 4) << 2;  // 0..60 step 4
  int cg = (t & 15) << 2;  // 0..60 step 4
  int dg = (t & 15) << 3;  // 0..120 step 8

  // ---- logits = (tq @ tc^T) * 10, masked
  float lg[4][4] = {};
  for (int kc = 0; kc < 128; kc += 16) {
    __syncthreads();
    for (int i = t; i < 16 * 64; i += 256) {
      int q = i >> 4, kk = i & 15;
      Atk[kk * 68 + q] = tq[q * 128 + kc + kk];
      Btk[kk * 68 + q] = tc[q * 128 + kc + kk];
    }
    __syncthreads();
    #pragma unroll
    for (int kk = 0; kk < 16; kk++) {
      float4 aq = *(const float4*)(Atk + kk * 68 + qg);
      float4 bc = *(const float4*)(Btk + kk * 68 + cg);
      lg[0][0] += aq.x * bc.x; lg[0][1] += aq.x * bc.y; lg[0][2] += aq.x * bc.z; lg[0][3] += aq.x * bc.w;
      lg[1][0] += aq.y * bc.x; lg[1][1] += aq.y * bc.y; lg[1][2] += aq.y * bc.z; lg[1][3] += aq.y * bc.w;
      lg[2][0] += aq.z * bc.x; lg[2][1] += aq.z * bc.y; lg[2][2] += aq.z * bc.z; lg[2][3] += aq.z * bc.w;
      lg[3][0] += aq.w * bc.x; lg[3][1] += aq.w * bc.y; lg[3][2] += aq.w * bc.z; lg[3][3] += aq.w * bc.w;
    }
  }
  #pragma unroll
  for (int j = 0; j < 4; j++)
    #pragma unroll
    for (int i = 0; i < 4; i++) {
      int q = qg + j, c = cg + i;
      SL[q * 65 + c] = (q < qs && c < cs) ? lg[j][i] * 10.0f : -1e9f;
    }
  __syncthreads();

  // ---- both softmaxes (different waves)
  if (t < 64) {
    int q = t;
    if (q < qs) {
      float m = -1e30f;
      for (int c = 0; c < 64; c++) m = fmaxf(m, SL[q * 65 + c]);
      float s = 0.f;
      for (int c = 0; c < 64; c++) s += __expf(SL[q * 65 + c] - m);
      float inv = 1.0f / s;
      for (int c = 0; c < 64; c++) SP[q * 65 + c] = __expf(SL[q * 65 + c] - m) * inv;
    } else {
      for (int c = 0; c < 64; c++) SP[q * 65 + c] = 0.f;
    }
  } else if (t < 128) {
    int c = t - 64;
    if (c < cs) {
      float m = -1e30f;
      for (int q = 0; q < 64; q++) m = fmaxf(m, SL[q * 65 + c]);
      float s = 0.f;
      for (int q = 0; q < 64; q++) s += __expf(SL[q * 65 + c] - m);
      float inv = 1.0f / s;
      for (int q = 0; q < 64; q++) SP2[q * 65 + c] = __expf(SL[q * 65 + c] - m) * inv;
    } else {
      for (int q = 0; q < 64; q++) SP2[q * 65 + c] = 0.f;
    }
  }
  __syncthreads();

  // ---- q_score: sum relu(sq - q_to_c @ sc)
  float al[4][8] = {};
  for (int c = 0; c < 64; c++) {
    float p0 = SP[(qg + 0) * 65 + c];
    float p1 = SP[(qg + 1) * 65 + c];
    float p2 = SP[(qg + 2) * 65 + c];
    float p3 = SP[(qg + 3) * 65 + c];
    float4 s0 = *(const float4*)(sc + c * 128 + dg);
    float4 s1 = *(const float4*)(sc + c * 128 + dg + 4);
    al[0][0] += p0 * s0.x; al[0][1] += p0 * s0.y; al[0][2] += p0 * s0.z; al[0][3] += p0 * s0.w;
    al[0][4] += p0 * s1.x; al[0][5] += p0 * s1.y; al[0][6] += p0 * s1.z; al[0][7] += p0 * s1.w;
    al[1][0] += p1 * s0.x; al[1][1] += p1 * s0.y; al[1][2] += p1 * s0.z; al[1][3] += p1 * s0.w;
    al[1][4] += p1 * s1.x; al[1][5] += p1 * s1.y; al[1][6] += p1 * s1.z; al[1][7] += p1 * s1.w;
    al[2][0] += p2 * s0.x; al[2][1] += p2 * s0.y; al[2][2] += p2 * s0.z; al[2][3] += p2 * s0.w;
    al[2][4] += p2 * s1.x; al[2][5] += p2 * s1.y; al[2][6] += p2 * s1.z; al[2][7] += p2 * s1.w;
    al[3][0] += p3 * s0.x; al[3][1] += p3 * s0.y; al[3][2] += p3 * s0.z; al[3][3] += p3 * s0.w;
    al[3][4] += p3 * s1.x; al[3][5] += p3 * s1.y; al[3][6] += p3 * s1.z; al[3][7] += p3 * s1.w;
  }
  float qpart = 0.f;
  #pragma unroll
  for (int j = 0; j < 4; j++) {
    float4 a0 = *(const float4*)(sq + (qg + j) * 128 + dg);
    float4 a1 = *(const float4*)(sq + (qg + j) * 128 + dg + 4);
    qpart += fmaxf(a0.x - al[j][0], 0.f) + fmaxf(a0.y - al[j][1], 0.f)
           + fmaxf(a0.z - al[j][2], 0.f) + fmaxf(a0.w - al[j][3], 0.f)
           + fmaxf(a1.x - al[j][4], 0.f) + fmaxf(a1.y - al[j][5], 0.f)
           + fmaxf(a1.z - al[j][6], 0.f) + fmaxf(a1.w - al[j][7], 0.f);
  }

  // ---- c_score: sum relu(sc - c_to_q^T @ sq)
  float al2[4][8] = {};
  for (int q = 0; q < 64; q++) {
    float p0 = SP2[q * 65 + qg + 0];
    float p1 = SP2[q * 65 + qg + 1];
    float p2 = SP2[q * 65 + qg + 2];
    float p3 = SP2[q * 65 + qg + 3];
    float4 s0 = *(const float4*)(sq + q * 128 + dg);
    float4 s1 = *(const float4*)(sq + q * 128 + dg + 4);
    al2[0][0] += p0 * s0.x; al2[0][1] += p0 * s0.y; al2[0][2] += p0 * s0.z; al2[0][3] += p0 * s0.w;
    al2[0][4] += p0 * s1.x; al2[0][5] += p0 * s1.y; al2[0][6] += p0 * s1.z; al2[0][7] += p0 * s1.w;
    al2[1][0] += p1 * s0.x; al2[1][1] += p1 * s0.y; al2[1][2] += p1 * s0.z; al2[1][3] += p1 * s0.w;
    al2[1][4] += p1 * s1.x; al2[1][5] += p1 * s1.y; al2[1][6] += p1 * s1.z; al2[1][7] += p1 * s1.w;
    al2[2][0] += p2 * s0.x; al2[2][1] += p2 * s0.y; al2[2][2] += p2 * s0.z; al2[2][3] += p2 * s0.w;
    al2[2][4] += p2 * s1.x; al2[2][5] += p2 * s1.y; al2[2][6] += p2 * s1.z; al2[2][7] += p2 * s1.w;
    al2[3][0] += p3 * s0.x; al2[3][1] += p3 * s0.y; al2[3][2] += p3 * s0.z; al2[3][3] += p3 * s0.w;
    al2[3][4] += p3 * s1.x; al2[3][5] += p3 * s1.y; al2[3][6] += p3 * s1.z; al2[3][7] += p3 * s1.w;
  }
  float cpart = 0.f;
  #pragma unroll
  for (int j = 0; j < 4; j++) {
    float4 b0 = *(const float4*)(sc + (qg + j) * 128 + dg);
    float4 b1 = *(const float4*)(sc + (qg + j) * 128 + dg + 4);
    cpart += fmaxf(b0.x - al2[j][0], 0.f) + fmaxf(b0.y - al2[j][1], 0.f)
           + fmaxf(b0.z - al2[j][2], 0.f) + fmaxf(b0.w - al2[j][3], 0.f)
           + fmaxf(b1.x - al2[j][4], 0.f) + fmaxf(b1.y - al2[j][5], 0.f)
           + fmaxf(b1.z - al2[j][6], 0.f) + fmaxf(b1.w - al2[j][7], 0.f);
  }

  // ---- reduce
  for (int off = 32; off > 0; off >>= 1) {
    qpart += __shfl_down(qpart, off);
    cpart += __shfl_down(cpart, off);
  }
  int wv = t >> 6;
  if ((t & 63) == 0) { red[wv] = qpart; red[wv + 4] = cpart; }
  __syncthreads();
  if (t == 0) {
    float qsum = red[0] + red[1] + red[2] + red[3];
    float csum = red[4] + red[5] + red[6] + red[7];
    out[b] = fminf(-qsum, -csum);
  }
}

// ---------------- launch ----------------
extern "C" void kernel_launch(void* const* d_in, const int* in_sizes, int n_in,
                              void* d_out, int out_size, void* d_ws, size_t ws_size,
                              hipStream_t stream)
{
  const float* nf  = (const float*)d_in[0];
  const float* ef  = (const float*)d_in[1];
  const int* from_idx = (const int*)d_in[2];
  const int* to_idx   = (const int*)d_in[3];
  const int* pos      = (const int*)d_in[4];
  const int* qsz      = (const int*)d_in[5];
  const int* csz      = (const int*)d_in[6];
  const float* W_node = (const float*)d_in[7];
  const float* b_node = (const float*)d_in[8];
  const float* W_edge = (const float*)d_in[9];
  const float* b_edge = (const float*)d_in[10];
  const float* W1 = (const float*)d_in[11];
  const float* b1 = (const float*)d_in[12];
  const float* W2 = (const float*)d_in[13];
  const float* b2 = (const float*)d_in[14];
  const float* Wu = (const float*)d_in[15];
  const float* bu = (const float*)d_in[16];
  const float* Wa1 = (const float*)d_in[17];
  const float* ba1 = (const float*)d_in[18];
  const float* Wa2 = (const float*)d_in[19];
  const float* ba2 = (const float*)d_in[20];
  float* out = (float*)d_out;

  int N = in_sizes[0] / NODE_F;
  int E = in_sizes[1] / EDGE_F;

  float* h    = (float*)d_ws;
  float* e    = h + (size_t)N * D;
  float* agg  = e + (size_t)E * EDIM;
  float* flat = agg + (size_t)N * 256;
  float* tfb  = flat + (size_t)2 * B_PAIRS * MAXN * D;

  hipMemsetAsync(flat, 0, (size_t)2 * B_PAIRS * MAXN * D * sizeof(float), stream);

  encode_nodes<<<(N + 1) / 2, 256, 0, stream>>>(nf, W_node, b_node, h, N);
  encode_edges<<<(E + 3) / 4, 256, 0, stream>>>(ef, W_edge, b_edge, e, E);

  for (int s = 0; s < PROP_STEPS; s++) {
    hipMemsetAsync(agg, 0, (size_t)N * 256 * sizeof(float), stream);
    msg_kernel<<<(E + MT - 1) / MT, 256, 0, stream>>>(h, e, from_idx, to_idx,
                                                      W1, b1, W2, b2, agg, E);
    update_kernel<<<(N + MTU - 1) / MTU, 256, 0, stream>>>(h, agg, Wu, bu, N);
  }

  scatter_kernel<<<(N * D + 255) / 256, 256, 0, stream>>>(h, pos, flat, N);
  attfeat_kernel<<<(2 * B_PAIRS * MAXN) / MTA, 256, 0, stream>>>(flat, Wa1, ba1, Wa2, ba2,
                                                                 qsz, csz, tfb);
  score_kernel<<<B_PAIRS, 256, 0, stream>>>(tfb, flat, qsz, csz, out);
}

// Round 3
// 1436.863 us; speedup vs baseline: 2.7095x; 2.7095x over previous
//
#include <hip/hip_runtime.h>

#define D 128
#define EDIM 64
#define NODE_F 32
#define EDGE_F 16
#define B_PAIRS 256
#define MAXN 64
#define PROP_STEPS 3

#define MTU 32    // nodes per block in update kernel
#define MTA 32    // rows per block in attfeat kernel
#define KC 16     // k-panel size for LDS-staged weights (fp32 kernels)

typedef __attribute__((ext_vector_type(8))) short short8;
typedef __attribute__((ext_vector_type(16))) float floatx16;

__device__ __forceinline__ short f2bf(float x) {
  unsigned u = __float_as_uint(x);
  u = (u + 0x7fff + ((u >> 16) & 1)) >> 16;   // RNE
  return (short)u;
}

// ---------------- weight prep: fp32 [K][256] -> bf16 panels [p][n=256][40] ----------------
// W1: K=320 -> 10 panels of 32 k (padded to 40); W2: K=256 -> 8 panels.
__global__ __launch_bounds__(256) void prep_w(
    const float* __restrict__ W1, const float* __restrict__ W2,
    short* __restrict__ W1p, short* __restrict__ W2p)
{
  int idx = blockIdx.x * 256 + threadIdx.x;
  if (idx < 10 * 10240) {
    int p = idx / 10240, rem = idx - p * 10240;
    int n = rem / 40, kk = rem - n * 40;
    W1p[idx] = (kk < 32) ? f2bf(W1[(size_t)(p * 32 + kk) * 256 + n]) : (short)0;
  } else {
    int i2 = idx - 10 * 10240;
    if (i2 < 8 * 10240) {
      int p = i2 / 10240, rem = i2 - p * 10240;
      int n = rem / 40, kk = rem - n * 40;
      W2p[i2] = (kk < 32) ? f2bf(W2[(size_t)(p * 32 + kk) * 256 + n]) : (short)0;
    }
  }
}

// ---------------- encoders ----------------
__global__ __launch_bounds__(256) void encode_nodes(
    const float* __restrict__ nf, const float* __restrict__ W,
    const float* __restrict__ bias, float* __restrict__ h,
    short* __restrict__ hb, int N)
{
  int t = threadIdx.x;
  int n = blockIdx.x * 2 + (t >> 7);
  int c = t & 127;
  if (n >= N) return;
  float acc = bias[c];
  #pragma unroll
  for (int k = 0; k < NODE_F; k++)
    acc += nf[(size_t)n * NODE_F + k] * W[k * D + c];
  h[(size_t)n * D + c] = acc;
  hb[(size_t)n * D + c] = f2bf(acc);
}

__global__ __launch_bounds__(256) void encode_edges(
    const float* __restrict__ ef, const float* __restrict__ W,
    const float* __restrict__ bias, short* __restrict__ eb, int E)
{
  int t = threadIdx.x;
  int eid = blockIdx.x * 4 + (t >> 6);
  int c = t & 63;
  if (eid >= E) return;
  float acc = bias[c];
  #pragma unroll
  for (int k = 0; k < EDGE_F; k++)
    acc += ef[(size_t)eid * EDGE_F + k] * W[k * EDIM + c];
  eb[(size_t)eid * EDIM + c] = f2bf(acc);
}

// ---------------- message + aggregate: bf16 MFMA ----------------
// M=64 edges/block, N=256, K1=320, K2=256. 4 waves; wave w owns cols [w*64, w*64+64).
// A (edge_in bf16) LDS rows padded to 328 shorts (656B, 16B-aligned, ~4-way banks).
// W panels staged from pre-transposed global layout [n=256][40] bf16 (80B rows).
__global__ __launch_bounds__(256, 2) void msg_mfma(
    const short* __restrict__ hb, const short* __restrict__ eb,
    const int* __restrict__ from_idx, const int* __restrict__ to_idx,
    const short* __restrict__ W1p, const float* __restrict__ b1,
    const short* __restrict__ W2p, const float* __restrict__ b2,
    float* __restrict__ agg, int E)
{
  __shared__ short sA[64 * 328];   // 41984B: edge_in, later hidden
  __shared__ short sB[256 * 40];   // 20480B: weight panel
  __shared__ int from_s[64], to_s[64];

  int t = threadIdx.x;
  int ln = t & 63, wv = t >> 6;
  int l31 = ln & 31, hi = ln >> 5;
  int cb = wv * 64;
  int e0 = blockIdx.x * 64;

  if (t < 64) {
    int eid = e0 + t;
    from_s[t] = (eid < E) ? from_idx[eid] : 0;
    to_s[t]   = (eid < E) ? to_idx[eid]   : 0;
  }
  __syncthreads();

  // stage A = [h[from] | h[to] | e] as bf16, row stride 328 shorts
  for (int i = t; i < 1024; i += 256) {
    int r = i >> 4, c = i & 15;
    *(short8*)(sA + r * 328 + c * 8) =
        *(const short8*)(hb + (size_t)from_s[r] * 128 + c * 8);
  }
  for (int i = t; i < 1024; i += 256) {
    int r = i >> 4, c = i & 15;
    *(short8*)(sA + r * 328 + 128 + c * 8) =
        *(const short8*)(hb + (size_t)to_s[r] * 128 + c * 8);
  }
  for (int i = t; i < 512; i += 256) {
    int r = i >> 3, c = i & 7;
    short8 v = {0, 0, 0, 0, 0, 0, 0, 0};
    if (e0 + r < E) v = *(const short8*)(eb + (size_t)(e0 + r) * 64 + c * 8);
    *(short8*)(sA + r * 328 + 256 + c * 8) = v;
  }

  floatx16 zero;
  #pragma unroll
  for (int i = 0; i < 16; i++) zero[i] = 0.f;

  // ---- GEMM1: hidden[64][256] = relu(edge_in @ W1 + b1)
  floatx16 acc[2][2];
  acc[0][0] = zero; acc[0][1] = zero; acc[1][0] = zero; acc[1][1] = zero;

  for (int p = 0; p < 10; p++) {
    __syncthreads();
    const short* src = W1p + (size_t)p * 10240;
    for (int i = t; i < 1280; i += 256)
      *(short8*)(sB + i * 8) = *(const short8*)(src + i * 8);
    __syncthreads();
    #pragma unroll
    for (int ks = 0; ks < 2; ks++) {
      int kg = p * 32 + ks * 16;
      short8 a0 = *(const short8*)(sA + (l31)      * 328 + kg + hi * 8);
      short8 a1 = *(const short8*)(sA + (32 + l31) * 328 + kg + hi * 8);
      short8 b0 = *(const short8*)(sB + (cb + l31)      * 40 + ks * 16 + hi * 8);
      short8 b1v = *(const short8*)(sB + (cb + 32 + l31) * 40 + ks * 16 + hi * 8);
      acc[0][0] = __builtin_amdgcn_mfma_f32_32x32x16_bf16(a0, b0,  acc[0][0], 0, 0, 0);
      acc[0][1] = __builtin_amdgcn_mfma_f32_32x32x16_bf16(a0, b1v, acc[0][1], 0, 0, 0);
      acc[1][0] = __builtin_amdgcn_mfma_f32_32x32x16_bf16(a1, b0,  acc[1][0], 0, 0, 0);
      acc[1][1] = __builtin_amdgcn_mfma_f32_32x32x16_bf16(a1, b1v, acc[1][1], 0, 0, 0);
    }
  }

  // relu + bias, write hidden (bf16) back into sA
  __syncthreads();
  float bv0 = b1[cb + l31], bv1 = b1[cb + 32 + l31];
  #pragma unroll
  for (int rg = 0; rg < 2; rg++)
    #pragma unroll
    for (int ct = 0; ct < 2; ct++) {
      float bv = ct ? bv1 : bv0;
      int col = cb + ct * 32 + l31;
      #pragma unroll
      for (int reg = 0; reg < 16; reg++) {
        int row = rg * 32 + (reg & 3) + 8 * (reg >> 2) + 4 * hi;
        sA[row * 328 + col] = f2bf(fmaxf(acc[rg][ct][reg] + bv, 0.f));
      }
    }
  __syncthreads();

  // ---- GEMM2: msg[64][256] = hidden @ W2 + b2
  floatx16 acc2[2][2];
  acc2[0][0] = zero; acc2[0][1] = zero; acc2[1][0] = zero; acc2[1][1] = zero;

  for (int p = 0; p < 8; p++) {
    __syncthreads();
    const short* src = W2p + (size_t)p * 10240;
    for (int i = t; i < 1280; i += 256)
      *(short8*)(sB + i * 8) = *(const short8*)(src + i * 8);
    __syncthreads();
    #pragma unroll
    for (int ks = 0; ks < 2; ks++) {
      int kg = p * 32 + ks * 16;
      short8 a0 = *(const short8*)(sA + (l31)      * 328 + kg + hi * 8);
      short8 a1 = *(const short8*)(sA + (32 + l31) * 328 + kg + hi * 8);
      short8 b0 = *(const short8*)(sB + (cb + l31)      * 40 + ks * 16 + hi * 8);
      short8 b1v = *(const short8*)(sB + (cb + 32 + l31) * 40 + ks * 16 + hi * 8);
      acc2[0][0] = __builtin_amdgcn_mfma_f32_32x32x16_bf16(a0, b0,  acc2[0][0], 0, 0, 0);
      acc2[0][1] = __builtin_amdgcn_mfma_f32_32x32x16_bf16(a0, b1v, acc2[0][1], 0, 0, 0);
      acc2[1][0] = __builtin_amdgcn_mfma_f32_32x32x16_bf16(a1, b0,  acc2[1][0], 0, 0, 0);
      acc2[1][1] = __builtin_amdgcn_mfma_f32_32x32x16_bf16(a1, b1v, acc2[1][1], 0, 0, 0);
    }
  }

  // segment-sum via fp32 atomics
  float b20 = b2[cb + l31], b21 = b2[cb + 32 + l31];
  #pragma unroll
  for (int rg = 0; rg < 2; rg++)
    #pragma unroll
    for (int ct = 0; ct < 2; ct++) {
      float bv = ct ? b21 : b20;
      int col = cb + ct * 32 + l31;
      #pragma unroll
      for (int reg = 0; reg < 16; reg++) {
        int grow = rg * 32 + (reg & 3) + 8 * (reg >> 2) + 4 * hi;
        if (e0 + grow < E) {
          unsafeAtomicAdd(agg + (size_t)to_s[grow] * 256 + col, acc2[rg][ct][reg] + bv);
        }
      }
    }
}

// ---------------- node update (fp32) ----------------
__global__ __launch_bounds__(256, 2) void update_kernel(
    float* __restrict__ h, short* __restrict__ hbf, const float* __restrict__ agg,
    const float* __restrict__ Wu, const float* __restrict__ bu, int N)
{
  __shared__ float sA[MTU * 384];
  __shared__ float sW[KC * 128];
  int t = threadIdx.x, wv = t >> 6, ln = t & 63;
  int n0 = blockIdx.x * MTU;

  for (int i = t * 4; i < MTU * 384; i += 1024) {
    int r = i / 384, c = i - r * 384;
    int n = n0 + r;
    float4 v = {0.f, 0.f, 0.f, 0.f};
    if (n < N) {
      if (c < 128) v = *(const float4*)(h   + (size_t)n * D + c);
      else         v = *(const float4*)(agg + (size_t)n * 256 + (c - 128));
    }
    *(float4*)(sA + i) = v;
  }

  float2 bb = *(const float2*)(bu + ln * 2);
  float acc[8][2];
  #pragma unroll
  for (int j = 0; j < 8; j++) { acc[j][0] = bb.x; acc[j][1] = bb.y; }

  for (int kc = 0; kc < 384; kc += KC) {
    __syncthreads();
    for (int i = t * 4; i < KC * 128; i += 1024) {
      int kk = i >> 7, c = i & 127;
      *(float4*)(sW + i) = *(const float4*)(Wu + (size_t)(kc + kk) * 128 + c);
    }
    __syncthreads();
    #pragma unroll
    for (int k4 = 0; k4 < KC; k4 += 4) {
      float4 a[8];
      #pragma unroll
      for (int j = 0; j < 8; j++)
        a[j] = *(const float4*)(sA + (wv * 8 + j) * 384 + kc + k4);
      #pragma unroll
      for (int k2 = 0; k2 < 4; k2++) {
        float2 w = *(const float2*)(sW + (k4 + k2) * 128 + ln * 2);
        #pragma unroll
        for (int j = 0; j < 8; j++) {
          float av = (k2 == 0) ? a[j].x : (k2 == 1) ? a[j].y : (k2 == 2) ? a[j].z : a[j].w;
          acc[j][0] += av * w.x; acc[j][1] += av * w.y;
        }
      }
    }
  }

  #pragma unroll
  for (int j = 0; j < 8; j++) {
    int n = n0 + wv * 8 + j;
    if (n < N) {
      float2* p = (float2*)(h + (size_t)n * D + ln * 2);
      float2 old = *p;
      float2 nv = { old.x + acc[j][0], old.y + acc[j][1] };
      *p = nv;
      int packed = (int)(unsigned short)f2bf(nv.x) | ((int)(unsigned short)f2bf(nv.y) << 16);
      *(int*)(hbf + (size_t)n * D + ln * 2) = packed;
    }
  }
}

// ---------------- scatter into padded stacks ----------------
__global__ void scatter_kernel(const float* __restrict__ h, const int* __restrict__ pos,
                               float* __restrict__ flat, int N)
{
  int idx = blockIdx.x * 256 + threadIdx.x;
  if (idx >= N * D) return;
  int n = idx >> 7, c = idx & 127;
  flat[(size_t)pos[n] * D + c] = h[idx];
}

// ---------------- attention features (fp32) ----------------
__global__ __launch_bounds__(256) void attfeat_kernel(
    const float* __restrict__ flat,
    const float* __restrict__ Wa1, const float* __restrict__ ba1,
    const float* __restrict__ Wa2, const float* __restrict__ ba2,
    const int* __restrict__ qsizes, const int* __restrict__ csizes,
    float* __restrict__ tf)
{
  __shared__ float sA[MTA * 128];
  __shared__ float sW[KC * 128];
  int t = threadIdx.x, wv = t >> 6, ln = t & 63;
  int r0 = blockIdx.x * MTA;

  for (int i = t * 4; i < MTA * 128; i += 1024)
    *(float4*)(sA + i) = *(const float4*)(flat + (size_t)r0 * 128 + i);

  float2 bb = *(const float2*)(ba1 + ln * 2);
  float acc[8][2];
  #pragma unroll
  for (int j = 0; j < 8; j++) { acc[j][0] = bb.x; acc[j][1] = bb.y; }

  for (int kc = 0; kc < 128; kc += KC) {
    __syncthreads();
    for (int i = t * 4; i < KC * 128; i += 1024) {
      int kk = i >> 7, c = i & 127;
      *(float4*)(sW + i) = *(const float4*)(Wa1 + (size_t)(kc + kk) * 128 + c);
    }
    __syncthreads();
    #pragma unroll
    for (int k4 = 0; k4 < KC; k4 += 4) {
      float4 a[8];
      #pragma unroll
      for (int j = 0; j < 8; j++)
        a[j] = *(const float4*)(sA + (wv * 8 + j) * 128 + kc + k4);
      #pragma unroll
      for (int k2 = 0; k2 < 4; k2++) {
        float2 w = *(const float2*)(sW + (k4 + k2) * 128 + ln * 2);
        #pragma unroll
        for (int j = 0; j < 8; j++) {
          float av = (k2 == 0) ? a[j].x : (k2 == 1) ? a[j].y : (k2 == 2) ? a[j].z : a[j].w;
          acc[j][0] += av * w.x; acc[j][1] += av * w.y;
        }
      }
    }
  }

  __syncthreads();
  #pragma unroll
  for (int j = 0; j < 8; j++) {
    sA[(wv * 8 + j) * 128 + ln * 2 + 0] = fmaxf(acc[j][0], 0.f);
    sA[(wv * 8 + j) * 128 + ln * 2 + 1] = fmaxf(acc[j][1], 0.f);
  }

  float2 bb2 = *(const float2*)(ba2 + ln * 2);
  #pragma unroll
  for (int j = 0; j < 8; j++) { acc[j][0] = bb2.x; acc[j][1] = bb2.y; }

  for (int kc = 0; kc < 128; kc += KC) {
    __syncthreads();
    for (int i = t * 4; i < KC * 128; i += 1024) {
      int kk = i >> 7, c = i & 127;
      *(float4*)(sW + i) = *(const float4*)(Wa2 + (size_t)(kc + kk) * 128 + c);
    }
    __syncthreads();
    #pragma unroll
    for (int k4 = 0; k4 < KC; k4 += 4) {
      float4 a[8];
      #pragma unroll
      for (int j = 0; j < 8; j++)
        a[j] = *(const float4*)(sA + (wv * 8 + j) * 128 + kc + k4);
      #pragma unroll
      for (int k2 = 0; k2 < 4; k2++) {
        float2 w = *(const float2*)(sW + (k4 + k2) * 128 + ln * 2);
        #pragma unroll
        for (int j = 0; j < 8; j++) {
          float av = (k2 == 0) ? a[j].x : (k2 == 1) ? a[j].y : (k2 == 2) ? a[j].z : a[j].w;
          acc[j][0] += av * w.x; acc[j][1] += av * w.y;
        }
      }
    }
  }

  #pragma unroll
  for (int j = 0; j < 8; j++) {
    int row = r0 + wv * 8 + j;
    int part = row >> 14, b = (row >> 6) & 255, pp = row & 63;
    int sz = part ? csizes[b] : qsizes[b];
    float m = (pp < sz) ? 1.f : 0.f;
    tf[(size_t)row * 128 + ln * 2 + 0] = acc[j][0] * m;
    tf[(size_t)row * 128 + ln * 2 + 1] = acc[j][1] * m;
  }
}

// ---------------- per-pair attention score ----------------
__global__ __launch_bounds__(256, 2) void score_kernel(
    const float* __restrict__ tf, const float* __restrict__ flat,
    const int* __restrict__ qsizes, const int* __restrict__ csizes,
    float* __restrict__ out)
{
  __shared__ float SL[64 * 65];
  __shared__ float SP[64 * 65];
  __shared__ float SP2[64 * 65];
  __shared__ float Atk[16 * 68];
  __shared__ float Btk[16 * 68];
  __shared__ float red[8];

  int b = blockIdx.x, t = threadIdx.x;
  const float* tq = tf + (size_t)b * 64 * 128;
  const float* tc = tf + ((size_t)16384 + (size_t)b * 64) * 128;
  const float* sq = flat + (size_t)b * 64 * 128;
  const float* sc = flat + ((size_t)16384 + (size_t)b * 64) * 128;
  int qs = qsizes[b], cs = csizes[b];

  int qg = (t >> 4) << 2;
  int cg = (t & 15) << 2;
  int dg = (t & 15) << 3;

  float lg[4][4] = {};
  for (int kc = 0; kc < 128; kc += 16) {
    __syncthreads();
    for (int i = t; i < 16 * 64; i += 256) {
      int q = i >> 4, kk = i & 15;
      Atk[kk * 68 + q] = tq[q * 128 + kc + kk];
      Btk[kk * 68 + q] = tc[q * 128 + kc + kk];
    }
    __syncthreads();
    #pragma unroll
    for (int kk = 0; kk < 16; kk++) {
      float4 aq = *(const float4*)(Atk + kk * 68 + qg);
      float4 bc = *(const float4*)(Btk + kk * 68 + cg);
      lg[0][0] += aq.x * bc.x; lg[0][1] += aq.x * bc.y; lg[0][2] += aq.x * bc.z; lg[0][3] += aq.x * bc.w;
      lg[1][0] += aq.y * bc.x; lg[1][1] += aq.y * bc.y; lg[1][2] += aq.y * bc.z; lg[1][3] += aq.y * bc.w;
      lg[2][0] += aq.z * bc.x; lg[2][1] += aq.z * bc.y; lg[2][2] += aq.z * bc.z; lg[2][3] += aq.z * bc.w;
      lg[3][0] += aq.w * bc.x; lg[3][1] += aq.w * bc.y; lg[3][2] += aq.w * bc.z; lg[3][3] += aq.w * bc.w;
    }
  }
  #pragma unroll
  for (int j = 0; j < 4; j++)
    #pragma unroll
    for (int i = 0; i < 4; i++) {
      int q = qg + j, c = cg + i;
      SL[q * 65 + c] = (q < qs && c < cs) ? lg[j][i] * 10.0f : -1e9f;
    }
  __syncthreads();

  if (t < 64) {
    int q = t;
    if (q < qs) {
      float m = -1e30f;
      for (int c = 0; c < 64; c++) m = fmaxf(m, SL[q * 65 + c]);
      float s = 0.f;
      for (int c = 0; c < 64; c++) s += __expf(SL[q * 65 + c] - m);
      float inv = 1.0f / s;
      for (int c = 0; c < 64; c++) SP[q * 65 + c] = __expf(SL[q * 65 + c] - m) * inv;
    } else {
      for (int c = 0; c < 64; c++) SP[q * 65 + c] = 0.f;
    }
  } else if (t < 128) {
    int c = t - 64;
    if (c < cs) {
      float m = -1e30f;
      for (int q = 0; q < 64; q++) m = fmaxf(m, SL[q * 65 + c]);
      float s = 0.f;
      for (int q = 0; q < 64; q++) s += __expf(SL[q * 65 + c] - m);
      float inv = 1.0f / s;
      for (int q = 0; q < 64; q++) SP2[q * 65 + c] = __expf(SL[q * 65 + c] - m) * inv;
    } else {
      for (int q = 0; q < 64; q++) SP2[q * 65 + c] = 0.f;
    }
  }
  __syncthreads();

  float al[4][8] = {};
  for (int c = 0; c < 64; c++) {
    float p0 = SP[(qg + 0) * 65 + c];
    float p1 = SP[(qg + 1) * 65 + c];
    float p2 = SP[(qg + 2) * 65 + c];
    float p3 = SP[(qg + 3) * 65 + c];
    float4 s0 = *(const float4*)(sc + c * 128 + dg);
    float4 s1 = *(const float4*)(sc + c * 128 + dg + 4);
    al[0][0] += p0 * s0.x; al[0][1] += p0 * s0.y; al[0][2] += p0 * s0.z; al[0][3] += p0 * s0.w;
    al[0][4] += p0 * s1.x; al[0][5] += p0 * s1.y; al[0][6] += p0 * s1.z; al[0][7] += p0 * s1.w;
    al[1][0] += p1 * s0.x; al[1][1] += p1 * s0.y; al[1][2] += p1 * s0.z; al[1][3] += p1 * s0.w;
    al[1][4] += p1 * s1.x; al[1][5] += p1 * s1.y; al[1][6] += p1 * s1.z; al[1][7] += p1 * s1.w;
    al[2][0] += p2 * s0.x; al[2][1] += p2 * s0.y; al[2][2] += p2 * s0.z; al[2][3] += p2 * s0.w;
    al[2][4] += p2 * s1.x; al[2][5] += p2 * s1.y; al[2][6] += p2 * s1.z; al[2][7] += p2 * s1.w;
    al[3][0] += p3 * s0.x; al[3][1] += p3 * s0.y; al[3][2] += p3 * s0.z; al[3][3] += p3 * s0.w;
    al[3][4] += p3 * s1.x; al[3][5] += p3 * s1.y; al[3][6] += p3 * s1.z; al[3][7] += p3 * s1.w;
  }
  float qpart = 0.f;
  #pragma unroll
  for (int j = 0; j < 4; j++) {
    float4 a0 = *(const float4*)(sq + (qg + j) * 128 + dg);
    float4 a1 = *(const float4*)(sq + (qg + j) * 128 + dg + 4);
    qpart += fmaxf(a0.x - al[j][0], 0.f) + fmaxf(a0.y - al[j][1], 0.f)
           + fmaxf(a0.z - al[j][2], 0.f) + fmaxf(a0.w - al[j][3], 0.f)
           + fmaxf(a1.x - al[j][4], 0.f) + fmaxf(a1.y - al[j][5], 0.f)
           + fmaxf(a1.z - al[j][6], 0.f) + fmaxf(a1.w - al[j][7], 0.f);
  }

  float al2[4][8] = {};
  for (int q = 0; q < 64; q++) {
    float p0 = SP2[q * 65 + qg + 0];
    float p1 = SP2[q * 65 + qg + 1];
    float p2 = SP2[q * 65 + qg + 2];
    float p3 = SP2[q * 65 + qg + 3];
    float4 s0 = *(const float4*)(sq + q * 128 + dg);
    float4 s1 = *(const float4*)(sq + q * 128 + dg + 4);
    al2[0][0] += p0 * s0.x; al2[0][1] += p0 * s0.y; al2[0][2] += p0 * s0.z; al2[0][3] += p0 * s0.w;
    al2[0][4] += p0 * s1.x; al2[0][5] += p0 * s1.y; al2[0][6] += p0 * s1.z; al2[0][7] += p0 * s1.w;
    al2[1][0] += p1 * s0.x; al2[1][1] += p1 * s0.y; al2[1][2] += p1 * s0.z; al2[1][3] += p1 * s0.w;
    al2[1][4] += p1 * s1.x; al2[1][5] += p1 * s1.y; al2[1][6] += p1 * s1.z; al2[1][7] += p1 * s1.w;
    al2[2][0] += p2 * s0.x; al2[2][1] += p2 * s0.y; al2[2][2] += p2 * s0.z; al2[2][3] += p2 * s0.w;
    al2[2][4] += p2 * s1.x; al2[2][5] += p2 * s1.y; al2[2][6] += p2 * s1.z; al2[2][7] += p2 * s1.w;
    al2[3][0] += p3 * s0.x; al2[3][1] += p3 * s0.y; al2[3][2] += p3 * s0.z; al2[3][3] += p3 * s0.w;
    al2[3][4] += p3 * s1.x; al2[3][5] += p3 * s1.y; al2[3][6] += p3 * s1.z; al2[3][7] += p3 * s1.w;
  }
  float cpart = 0.f;
  #pragma unroll
  for (int j = 0; j < 4; j++) {
    float4 b0 = *(const float4*)(sc + (qg + j) * 128 + dg);
    float4 b1 = *(const float4*)(sc + (qg + j) * 128 + dg + 4);
    cpart += fmaxf(b0.x - al2[j][0], 0.f) + fmaxf(b0.y - al2[j][1], 0.f)
           + fmaxf(b0.z - al2[j][2], 0.f) + fmaxf(b0.w - al2[j][3], 0.f)
           + fmaxf(b1.x - al2[j][4], 0.f) + fmaxf(b1.y - al2[j][5], 0.f)
           + fmaxf(b1.z - al2[j][6], 0.f) + fmaxf(b1.w - al2[j][7], 0.f);
  }

  for (int off = 32; off > 0; off >>= 1) {
    qpart += __shfl_down(qpart, off);
    cpart += __shfl_down(cpart, off);
  }
  int wv = t >> 6;
  if ((t & 63) == 0) { red[wv] = qpart; red[wv + 4] = cpart; }
  __syncthreads();
  if (t == 0) {
    float qsum = red[0] + red[1] + red[2] + red[3];
    float csum = red[4] + red[5] + red[6] + red[7];
    out[b] = fminf(-qsum, -csum);
  }
}

// ---------------- launch ----------------
extern "C" void kernel_launch(void* const* d_in, const int* in_sizes, int n_in,
                              void* d_out, int out_size, void* d_ws, size_t ws_size,
                              hipStream_t stream)
{
  const float* nf  = (const float*)d_in[0];
  const float* ef  = (const float*)d_in[1];
  const int* from_idx = (const int*)d_in[2];
  const int* to_idx   = (const int*)d_in[3];
  const int* pos      = (const int*)d_in[4];
  const int* qsz      = (const int*)d_in[5];
  const int* csz      = (const int*)d_in[6];
  const float* W_node = (const float*)d_in[7];
  const float* b_node = (const float*)d_in[8];
  const float* W_edge = (const float*)d_in[9];
  const float* b_edge = (const float*)d_in[10];
  const float* W1 = (const float*)d_in[11];
  const float* b1 = (const float*)d_in[12];
  const float* W2 = (const float*)d_in[13];
  const float* b2 = (const float*)d_in[14];
  const float* Wu = (const float*)d_in[15];
  const float* bu = (const float*)d_in[16];
  const float* Wa1 = (const float*)d_in[17];
  const float* ba1 = (const float*)d_in[18];
  const float* Wa2 = (const float*)d_in[19];
  const float* ba2 = (const float*)d_in[20];
  float* out = (float*)d_out;

  int N = in_sizes[0] / NODE_F;
  int E = in_sizes[1] / EDGE_F;

  float* h    = (float*)d_ws;
  float* agg  = h + (size_t)N * D;
  float* flat = agg + (size_t)N * 256;
  float* tfb  = flat + (size_t)2 * B_PAIRS * MAXN * D;
  short* hb   = (short*)(tfb + (size_t)2 * B_PAIRS * MAXN * D);
  short* eb   = hb + (size_t)N * D;
  short* W1p  = eb + (size_t)E * EDIM;
  short* W2p  = W1p + 10 * 10240;

  hipMemsetAsync(flat, 0, (size_t)2 * B_PAIRS * MAXN * D * sizeof(float), stream);

  prep_w<<<720, 256, 0, stream>>>(W1, W2, W1p, W2p);
  encode_nodes<<<(N + 1) / 2, 256, 0, stream>>>(nf, W_node, b_node, h, hb, N);
  encode_edges<<<(E + 3) / 4, 256, 0, stream>>>(ef, W_edge, b_edge, eb, E);

  for (int s = 0; s < PROP_STEPS; s++) {
    hipMemsetAsync(agg, 0, (size_t)N * 256 * sizeof(float), stream);
    msg_mfma<<<(E + 63) / 64, 256, 0, stream>>>(hb, eb, from_idx, to_idx,
                                                W1p, b1, W2p, b2, agg, E);
    update_kernel<<<(N + MTU - 1) / MTU, 256, 0, stream>>>(h, hb, agg, Wu, bu, N);
  }

  scatter_kernel<<<(N * D + 255) / 256, 256, 0, stream>>>(h, pos, flat, N);
  attfeat_kernel<<<(2 * B_PAIRS * MAXN) / MTA, 256, 0, stream>>>(flat, Wa1, ba1, Wa2, ba2,
                                                                 qsz, csz, tfb);
  score_kernel<<<B_PAIRS, 256, 0, stream>>>(tfb, flat, qsz, csz, out);
}

// Round 4
// 1044.701 us; speedup vs baseline: 3.7266x; 1.3754x over previous
//
#include <hip/hip_runtime.h>

#define D 128
#define EDIM 64
#define NODE_F 32
#define EDGE_F 16
#define B_PAIRS 256
#define MAXN 64
#define PROP_STEPS 3

#define MTA 32    // rows per block in attfeat kernel
#define KC 16     // k-panel size for LDS-staged weights (fp32 kernels)

typedef __attribute__((ext_vector_type(8))) short short8;
typedef __attribute__((ext_vector_type(16))) float floatx16;

__device__ __forceinline__ short f2bf(float x) {
  unsigned u = __float_as_uint(x);
  u = (u + 0x7fff + ((u >> 16) & 1)) >> 16;   // RNE
  return (short)u;
}

// ---------------- weight prep ----------------
// W1 [320][256] -> 10 panels [n=256][40shorts]; W2 [256][256] -> 8 panels;
// Wu [384][128] -> 12 panels [n=128][40shorts].
__global__ __launch_bounds__(256) void prep_w(
    const float* __restrict__ W1, const float* __restrict__ W2,
    const float* __restrict__ Wu,
    short* __restrict__ W1p, short* __restrict__ W2p, short* __restrict__ Wup)
{
  int idx = blockIdx.x * 256 + threadIdx.x;
  if (idx < 102400) {
    int p = idx / 10240, rem = idx - p * 10240;
    int n = rem / 40, kk = rem - n * 40;
    W1p[idx] = (kk < 32) ? f2bf(W1[(size_t)(p * 32 + kk) * 256 + n]) : (short)0;
  } else if (idx < 184320) {
    int i2 = idx - 102400;
    int p = i2 / 10240, rem = i2 - p * 10240;
    int n = rem / 40, kk = rem - n * 40;
    W2p[i2] = (kk < 32) ? f2bf(W2[(size_t)(p * 32 + kk) * 256 + n]) : (short)0;
  } else if (idx < 245760) {
    int i3 = idx - 184320;
    int p = i3 / 5120, rem = i3 - p * 5120;
    int n = rem / 40, kk = rem - n * 40;
    Wup[i3] = (kk < 32) ? f2bf(Wu[(size_t)(p * 32 + kk) * 128 + n]) : (short)0;
  }
}

// ---------------- encoders ----------------
__global__ __launch_bounds__(256) void encode_nodes(
    const float* __restrict__ nf, const float* __restrict__ W,
    const float* __restrict__ bias, float* __restrict__ h,
    short* __restrict__ hb, int N)
{
  int t = threadIdx.x;
  int n = blockIdx.x * 2 + (t >> 7);
  int c = t & 127;
  if (n >= N) return;
  float acc = bias[c];
  #pragma unroll
  for (int k = 0; k < NODE_F; k++)
    acc += nf[(size_t)n * NODE_F + k] * W[k * D + c];
  h[(size_t)n * D + c] = acc;
  hb[(size_t)n * D + c] = f2bf(acc);
}

__global__ __launch_bounds__(256) void encode_edges(
    const float* __restrict__ ef, const float* __restrict__ W,
    const float* __restrict__ bias, short* __restrict__ eb, int E)
{
  int t = threadIdx.x;
  int eid = blockIdx.x * 4 + (t >> 6);
  int c = t & 63;
  if (eid >= E) return;
  float acc = bias[c];
  #pragma unroll
  for (int k = 0; k < EDGE_F; k++)
    acc += ef[(size_t)eid * EDGE_F + k] * W[k * EDIM + c];
  eb[(size_t)eid * EDIM + c] = f2bf(acc);
}

// ---------------- message + aggregate: bf16 MFMA, register-prefetched weights ----------------
__global__ __launch_bounds__(256, 2) void msg_mfma(
    const short* __restrict__ hb, const short* __restrict__ eb,
    const int* __restrict__ from_idx, const int* __restrict__ to_idx,
    const short* __restrict__ W1p, const float* __restrict__ b1,
    const short* __restrict__ W2p, const float* __restrict__ b2,
    float* __restrict__ agg, int E)
{
  __shared__ short sA[64 * 328];   // 41984B: edge_in, later hidden
  __shared__ short sB[256 * 40];   // 20480B: weight panel
  __shared__ int from_s[64], to_s[64];

  int t = threadIdx.x;
  int ln = t & 63, wv = t >> 6;
  int l31 = ln & 31, hi = ln >> 5;
  int cb = wv * 64;
  int e0 = blockIdx.x * 64;

  // prefetch W1 panel 0 into registers (in flight during A staging)
  short8 wreg[5];
  #pragma unroll
  for (int u = 0; u < 5; u++)
    wreg[u] = *(const short8*)(W1p + (size_t)(t + u * 256) * 8);

  if (t < 64) {
    int eid = e0 + t;
    from_s[t] = (eid < E) ? from_idx[eid] : 0;
    to_s[t]   = (eid < E) ? to_idx[eid]   : 0;
  }
  __syncthreads();

  // stage A = [h[from] | h[to] | e] as bf16, row stride 328 shorts
  for (int i = t; i < 1024; i += 256) {
    int r = i >> 4, c = i & 15;
    *(short8*)(sA + r * 328 + c * 8) =
        *(const short8*)(hb + (size_t)from_s[r] * 128 + c * 8);
  }
  for (int i = t; i < 1024; i += 256) {
    int r = i >> 4, c = i & 15;
    *(short8*)(sA + r * 328 + 128 + c * 8) =
        *(const short8*)(hb + (size_t)to_s[r] * 128 + c * 8);
  }
  for (int i = t; i < 512; i += 256) {
    int r = i >> 3, c = i & 7;
    short8 v = {0, 0, 0, 0, 0, 0, 0, 0};
    if (e0 + r < E) v = *(const short8*)(eb + (size_t)(e0 + r) * 64 + c * 8);
    *(short8*)(sA + r * 328 + 256 + c * 8) = v;
  }

  floatx16 zero;
  #pragma unroll
  for (int i = 0; i < 16; i++) zero[i] = 0.f;

  // ---- GEMM1: hidden[64][256] = relu(edge_in @ W1 + b1)
  floatx16 acc[2][2];
  acc[0][0] = zero; acc[0][1] = zero; acc[1][0] = zero; acc[1][1] = zero;

  for (int p = 0; p < 10; p++) {
    __syncthreads();                  // all waves done reading sB (prev panel) / A staged
    #pragma unroll
    for (int u = 0; u < 5; u++)
      *(short8*)(sB + (size_t)(t + u * 256) * 8) = wreg[u];
    {
      const short* src = (p + 1 < 10) ? (W1p + (size_t)(p + 1) * 10240) : W2p;
      #pragma unroll
      for (int u = 0; u < 5; u++)
        wreg[u] = *(const short8*)(src + (size_t)(t + u * 256) * 8);
    }
    __syncthreads();
    #pragma unroll
    for (int ks = 0; ks < 2; ks++) {
      int kg = p * 32 + ks * 16;
      short8 a0 = *(const short8*)(sA + (l31)      * 328 + kg + hi * 8);
      short8 a1 = *(const short8*)(sA + (32 + l31) * 328 + kg + hi * 8);
      short8 b0 = *(const short8*)(sB + (cb + l31)      * 40 + ks * 16 + hi * 8);
      short8 b1v = *(const short8*)(sB + (cb + 32 + l31) * 40 + ks * 16 + hi * 8);
      acc[0][0] = __builtin_amdgcn_mfma_f32_32x32x16_bf16(a0, b0,  acc[0][0], 0, 0, 0);
      acc[0][1] = __builtin_amdgcn_mfma_f32_32x32x16_bf16(a0, b1v, acc[0][1], 0, 0, 0);
      acc[1][0] = __builtin_amdgcn_mfma_f32_32x32x16_bf16(a1, b0,  acc[1][0], 0, 0, 0);
      acc[1][1] = __builtin_amdgcn_mfma_f32_32x32x16_bf16(a1, b1v, acc[1][1], 0, 0, 0);
    }
  }

  // relu + bias, write hidden (bf16) back into sA (W2 panel 0 prefetch in flight)
  __syncthreads();
  float bv0 = b1[cb + l31], bv1 = b1[cb + 32 + l31];
  #pragma unroll
  for (int rg = 0; rg < 2; rg++)
    #pragma unroll
    for (int ct = 0; ct < 2; ct++) {
      float bv = ct ? bv1 : bv0;
      int col = cb + ct * 32 + l31;
      #pragma unroll
      for (int reg = 0; reg < 16; reg++) {
        int row = rg * 32 + (reg & 3) + 8 * (reg >> 2) + 4 * hi;
        sA[row * 328 + col] = f2bf(fmaxf(acc[rg][ct][reg] + bv, 0.f));
      }
    }

  // ---- GEMM2: msg[64][256] = hidden @ W2 + b2
  floatx16 acc2[2][2];
  acc2[0][0] = zero; acc2[0][1] = zero; acc2[1][0] = zero; acc2[1][1] = zero;

  for (int p = 0; p < 8; p++) {
    __syncthreads();
    #pragma unroll
    for (int u = 0; u < 5; u++)
      *(short8*)(sB + (size_t)(t + u * 256) * 8) = wreg[u];
    if (p + 1 < 8) {
      const short* src = W2p + (size_t)(p + 1) * 10240;
      #pragma unroll
      for (int u = 0; u < 5; u++)
        wreg[u] = *(const short8*)(src + (size_t)(t + u * 256) * 8);
    }
    __syncthreads();
    #pragma unroll
    for (int ks = 0; ks < 2; ks++) {
      int kg = p * 32 + ks * 16;
      short8 a0 = *(const short8*)(sA + (l31)      * 328 + kg + hi * 8);
      short8 a1 = *(const short8*)(sA + (32 + l31) * 328 + kg + hi * 8);
      short8 b0 = *(const short8*)(sB + (cb + l31)      * 40 + ks * 16 + hi * 8);
      short8 b1v = *(const short8*)(sB + (cb + 32 + l31) * 40 + ks * 16 + hi * 8);
      acc2[0][0] = __builtin_amdgcn_mfma_f32_32x32x16_bf16(a0, b0,  acc2[0][0], 0, 0, 0);
      acc2[0][1] = __builtin_amdgcn_mfma_f32_32x32x16_bf16(a0, b1v, acc2[0][1], 0, 0, 0);
      acc2[1][0] = __builtin_amdgcn_mfma_f32_32x32x16_bf16(a1, b0,  acc2[1][0], 0, 0, 0);
      acc2[1][1] = __builtin_amdgcn_mfma_f32_32x32x16_bf16(a1, b1v, acc2[1][1], 0, 0, 0);
    }
  }

  // segment-sum via fp32 atomics
  float b20 = b2[cb + l31], b21 = b2[cb + 32 + l31];
  #pragma unroll
  for (int rg = 0; rg < 2; rg++)
    #pragma unroll
    for (int ct = 0; ct < 2; ct++) {
      float bv = ct ? b21 : b20;
      int col = cb + ct * 32 + l31;
      #pragma unroll
      for (int reg = 0; reg < 16; reg++) {
        int grow = rg * 32 + (reg & 3) + 8 * (reg >> 2) + 4 * hi;
        if (e0 + grow < E) {
          unsafeAtomicAdd(agg + (size_t)to_s[grow] * 256 + col, acc2[rg][ct][reg] + bv);
        }
      }
    }
}

// ---------------- node update: bf16 MFMA ----------------
// h += concat(h, agg) @ Wu + bu.  M=32 nodes/block, K=384, N=128.
__global__ __launch_bounds__(256, 4) void update_mfma(
    float* __restrict__ h, short* __restrict__ hbf, const float* __restrict__ agg,
    const short* __restrict__ Wup, const float* __restrict__ bu, int N)
{
  __shared__ short sA[32 * 392];   // 25088B (row stride 784B: 16B-aligned)
  __shared__ short sB[128 * 40];   // 10240B

  int t = threadIdx.x;
  int ln = t & 63, wv = t >> 6;
  int l31 = ln & 31, hi = ln >> 5;
  int n0 = blockIdx.x * 32;

  // prefetch Wu panel 0 (640 short8 chunks over 256 threads)
  short8 wreg[3];
  #pragma unroll
  for (int u = 0; u < 3; u++) {
    int idx = t + u * 256;
    if (idx < 640) wreg[u] = *(const short8*)(Wup + (size_t)idx * 8);
  }

  // stage A: cols 0..127 = hbf[n], cols 128..383 = bf16(agg[n])
  for (int i = t; i < 512; i += 256) {
    int r = i >> 4, c = i & 15;
    short8 v = {0, 0, 0, 0, 0, 0, 0, 0};
    if (n0 + r < N) v = *(const short8*)(hbf + (size_t)(n0 + r) * 128 + c * 8);
    *(short8*)(sA + r * 392 + c * 8) = v;
  }
  for (int i = t; i < 2048; i += 256) {
    int r = i >> 6, c4 = i & 63;
    int2 pk = {0, 0};
    if (n0 + r < N) {
      float4 v = *(const float4*)(agg + (size_t)(n0 + r) * 256 + c4 * 4);
      pk.x = (int)(unsigned short)f2bf(v.x) | ((int)(unsigned short)f2bf(v.y) << 16);
      pk.y = (int)(unsigned short)f2bf(v.z) | ((int)(unsigned short)f2bf(v.w) << 16);
    }
    *(int2*)(sA + r * 392 + 128 + c4 * 4) = pk;
  }

  floatx16 acc;
  #pragma unroll
  for (int i = 0; i < 16; i++) acc[i] = 0.f;

  for (int p = 0; p < 12; p++) {
    __syncthreads();
    #pragma unroll
    for (int u = 0; u < 3; u++) {
      int idx = t + u * 256;
      if (idx < 640) *(short8*)(sB + (size_t)idx * 8) = wreg[u];
    }
    if (p + 1 < 12) {
      const short* src = Wup + (size_t)(p + 1) * 5120;
      #pragma unroll
      for (int u = 0; u < 3; u++) {
        int idx = t + u * 256;
        if (idx < 640) wreg[u] = *(const short8*)(src + (size_t)idx * 8);
      }
    }
    __syncthreads();
    #pragma unroll
    for (int ks = 0; ks < 2; ks++) {
      int kg = p * 32 + ks * 16;
      short8 a = *(const short8*)(sA + l31 * 392 + kg + hi * 8);
      short8 b = *(const short8*)(sB + (wv * 32 + l31) * 40 + ks * 16 + hi * 8);
      acc = __builtin_amdgcn_mfma_f32_32x32x16_bf16(a, b, acc, 0, 0, 0);
    }
  }

  int col = wv * 32 + l31;
  float bv = bu[col];
  #pragma unroll
  for (int reg = 0; reg < 16; reg++) {
    int row = (reg & 3) + 8 * (reg >> 2) + 4 * hi;
    int n = n0 + row;
    if (n < N) {
      float nv = h[(size_t)n * 128 + col] + acc[reg] + bv;
      h[(size_t)n * 128 + col] = nv;
      hbf[(size_t)n * 128 + col] = f2bf(nv);
    }
  }
}

// ---------------- scatter into padded stacks ----------------
__global__ void scatter_kernel(const float* __restrict__ h, const int* __restrict__ pos,
                               float* __restrict__ flat, int N)
{
  int idx = blockIdx.x * 256 + threadIdx.x;
  if (idx >= N * D) return;
  int n = idx >> 7, c = idx & 127;
  flat[(size_t)pos[n] * D + c] = h[idx];
}

// ---------------- attention features (fp32) ----------------
__global__ __launch_bounds__(256) void attfeat_kernel(
    const float* __restrict__ flat,
    const float* __restrict__ Wa1, const float* __restrict__ ba1,
    const float* __restrict__ Wa2, const float* __restrict__ ba2,
    const int* __restrict__ qsizes, const int* __restrict__ csizes,
    float* __restrict__ tf)
{
  __shared__ float sA[MTA * 128];
  __shared__ float sW[KC * 128];
  int t = threadIdx.x, wv = t >> 6, ln = t & 63;
  int r0 = blockIdx.x * MTA;

  for (int i = t * 4; i < MTA * 128; i += 1024)
    *(float4*)(sA + i) = *(const float4*)(flat + (size_t)r0 * 128 + i);

  float2 bb = *(const float2*)(ba1 + ln * 2);
  float acc[8][2];
  #pragma unroll
  for (int j = 0; j < 8; j++) { acc[j][0] = bb.x; acc[j][1] = bb.y; }

  for (int kc = 0; kc < 128; kc += KC) {
    __syncthreads();
    for (int i = t * 4; i < KC * 128; i += 1024) {
      int kk = i >> 7, c = i & 127;
      *(float4*)(sW + i) = *(const float4*)(Wa1 + (size_t)(kc + kk) * 128 + c);
    }
    __syncthreads();
    #pragma unroll
    for (int k4 = 0; k4 < KC; k4 += 4) {
      float4 a[8];
      #pragma unroll
      for (int j = 0; j < 8; j++)
        a[j] = *(const float4*)(sA + (wv * 8 + j) * 128 + kc + k4);
      #pragma unroll
      for (int k2 = 0; k2 < 4; k2++) {
        float2 w = *(const float2*)(sW + (k4 + k2) * 128 + ln * 2);
        #pragma unroll
        for (int j = 0; j < 8; j++) {
          float av = (k2 == 0) ? a[j].x : (k2 == 1) ? a[j].y : (k2 == 2) ? a[j].z : a[j].w;
          acc[j][0] += av * w.x; acc[j][1] += av * w.y;
        }
      }
    }
  }

  __syncthreads();
  #pragma unroll
  for (int j = 0; j < 8; j++) {
    sA[(wv * 8 + j) * 128 + ln * 2 + 0] = fmaxf(acc[j][0], 0.f);
    sA[(wv * 8 + j) * 128 + ln * 2 + 1] = fmaxf(acc[j][1], 0.f);
  }

  float2 bb2 = *(const float2*)(ba2 + ln * 2);
  #pragma unroll
  for (int j = 0; j < 8; j++) { acc[j][0] = bb2.x; acc[j][1] = bb2.y; }

  for (int kc = 0; kc < 128; kc += KC) {
    __syncthreads();
    for (int i = t * 4; i < KC * 128; i += 1024) {
      int kk = i >> 7, c = i & 127;
      *(float4*)(sW + i) = *(const float4*)(Wa2 + (size_t)(kc + kk) * 128 + c);
    }
    __syncthreads();
    #pragma unroll
    for (int k4 = 0; k4 < KC; k4 += 4) {
      float4 a[8];
      #pragma unroll
      for (int j = 0; j < 8; j++)
        a[j] = *(const float4*)(sA + (wv * 8 + j) * 128 + kc + k4);
      #pragma unroll
      for (int k2 = 0; k2 < 4; k2++) {
        float2 w = *(const float2*)(sW + (k4 + k2) * 128 + ln * 2);
        #pragma unroll
        for (int j = 0; j < 8; j++) {
          float av = (k2 == 0) ? a[j].x : (k2 == 1) ? a[j].y : (k2 == 2) ? a[j].z : a[j].w;
          acc[j][0] += av * w.x; acc[j][1] += av * w.y;
        }
      }
    }
  }

  #pragma unroll
  for (int j = 0; j < 8; j++) {
    int row = r0 + wv * 8 + j;
    int part = row >> 14, b = (row >> 6) & 255, pp = row & 63;
    int sz = part ? csizes[b] : qsizes[b];
    float m = (pp < sz) ? 1.f : 0.f;
    tf[(size_t)row * 128 + ln * 2 + 0] = acc[j][0] * m;
    tf[(size_t)row * 128 + ln * 2 + 1] = acc[j][1] * m;
  }
}

// ---------------- per-pair attention score ----------------
__global__ __launch_bounds__(256, 2) void score_kernel(
    const float* __restrict__ tf, const float* __restrict__ flat,
    const int* __restrict__ qsizes, const int* __restrict__ csizes,
    float* __restrict__ out)
{
  __shared__ float SL[64 * 65];
  __shared__ float SP[64 * 65];
  __shared__ float SP2[64 * 65];
  __shared__ float Atk[16 * 68];
  __shared__ float Btk[16 * 68];
  __shared__ float red[8];

  int b = blockIdx.x, t = threadIdx.x;
  const float* tq = tf + (size_t)b * 64 * 128;
  const float* tc = tf + ((size_t)16384 + (size_t)b * 64) * 128;
  const float* sq = flat + (size_t)b * 64 * 128;
  const float* sc = flat + ((size_t)16384 + (size_t)b * 64) * 128;
  int qs = qsizes[b], cs = csizes[b];

  int qg = (t >> 4) << 2;
  int cg = (t & 15) << 2;
  int dg = (t & 15) << 3;

  float lg[4][4] = {};
  for (int kc = 0; kc < 128; kc += 16) {
    __syncthreads();
    for (int i = t; i < 16 * 64; i += 256) {
      int q = i >> 4, kk = i & 15;
      Atk[kk * 68 + q] = tq[q * 128 + kc + kk];
      Btk[kk * 68 + q] = tc[q * 128 + kc + kk];
    }
    __syncthreads();
    #pragma unroll
    for (int kk = 0; kk < 16; kk++) {
      float4 aq = *(const float4*)(Atk + kk * 68 + qg);
      float4 bc = *(const float4*)(Btk + kk * 68 + cg);
      lg[0][0] += aq.x * bc.x; lg[0][1] += aq.x * bc.y; lg[0][2] += aq.x * bc.z; lg[0][3] += aq.x * bc.w;
      lg[1][0] += aq.y * bc.x; lg[1][1] += aq.y * bc.y; lg[1][2] += aq.y * bc.z; lg[1][3] += aq.y * bc.w;
      lg[2][0] += aq.z * bc.x; lg[2][1] += aq.z * bc.y; lg[2][2] += aq.z * bc.z; lg[2][3] += aq.z * bc.w;
      lg[3][0] += aq.w * bc.x; lg[3][1] += aq.w * bc.y; lg[3][2] += aq.w * bc.z; lg[3][3] += aq.w * bc.w;
    }
  }
  #pragma unroll
  for (int j = 0; j < 4; j++)
    #pragma unroll
    for (int i = 0; i < 4; i++) {
      int q = qg + j, c = cg + i;
      SL[q * 65 + c] = (q < qs && c < cs) ? lg[j][i] * 10.0f : -1e9f;
    }
  __syncthreads();

  if (t < 64) {
    int q = t;
    if (q < qs) {
      float m = -1e30f;
      for (int c = 0; c < 64; c++) m = fmaxf(m, SL[q * 65 + c]);
      float s = 0.f;
      for (int c = 0; c < 64; c++) s += __expf(SL[q * 65 + c] - m);
      float inv = 1.0f / s;
      for (int c = 0; c < 64; c++) SP[q * 65 + c] = __expf(SL[q * 65 + c] - m) * inv;
    } else {
      for (int c = 0; c < 64; c++) SP[q * 65 + c] = 0.f;
    }
  } else if (t < 128) {
    int c = t - 64;
    if (c < cs) {
      float m = -1e30f;
      for (int q = 0; q < 64; q++) m = fmaxf(m, SL[q * 65 + c]);
      float s = 0.f;
      for (int q = 0; q < 64; q++) s += __expf(SL[q * 65 + c] - m);
      float inv = 1.0f / s;
      for (int q = 0; q < 64; q++) SP2[q * 65 + c] = __expf(SL[q * 65 + c] - m) * inv;
    } else {
      for (int q = 0; q < 64; q++) SP2[q * 65 + c] = 0.f;
    }
  }
  __syncthreads();

  float al[4][8] = {};
  for (int c = 0; c < 64; c++) {
    float p0 = SP[(qg + 0) * 65 + c];
    float p1 = SP[(qg + 1) * 65 + c];
    float p2 = SP[(qg + 2) * 65 + c];
    float p3 = SP[(qg + 3) * 65 + c];
    float4 s0 = *(const float4*)(sc + c * 128 + dg);
    float4 s1 = *(const float4*)(sc + c * 128 + dg + 4);
    al[0][0] += p0 * s0.x; al[0][1] += p0 * s0.y; al[0][2] += p0 * s0.z; al[0][3] += p0 * s0.w;
    al[0][4] += p0 * s1.x; al[0][5] += p0 * s1.y; al[0][6] += p0 * s1.z; al[0][7] += p0 * s1.w;
    al[1][0] += p1 * s0.x; al[1][1] += p1 * s0.y; al[1][2] += p1 * s0.z; al[1][3] += p1 * s0.w;
    al[1][4] += p1 * s1.x; al[1][5] += p1 * s1.y; al[1][6] += p1 * s1.z; al[1][7] += p1 * s1.w;
    al[2][0] += p2 * s0.x; al[2][1] += p2 * s0.y; al[2][2] += p2 * s0.z; al[2][3] += p2 * s0.w;
    al[2][4] += p2 * s1.x; al[2][5] += p2 * s1.y; al[2][6] += p2 * s1.z; al[2][7] += p2 * s1.w;
    al[3][0] += p3 * s0.x; al[3][1] += p3 * s0.y; al[3][2] += p3 * s0.z; al[3][3] += p3 * s0.w;
    al[3][4] += p3 * s1.x; al[3][5] += p3 * s1.y; al[3][6] += p3 * s1.z; al[3][7] += p3 * s1.w;
  }
  float qpart = 0.f;
  #pragma unroll
  for (int j = 0; j < 4; j++) {
    float4 a0 = *(const float4*)(sq + (qg + j) * 128 + dg);
    float4 a1 = *(const float4*)(sq + (qg + j) * 128 + dg + 4);
    qpart += fmaxf(a0.x - al[j][0], 0.f) + fmaxf(a0.y - al[j][1], 0.f)
           + fmaxf(a0.z - al[j][2], 0.f) + fmaxf(a0.w - al[j][3], 0.f)
           + fmaxf(a1.x - al[j][4], 0.f) + fmaxf(a1.y - al[j][5], 0.f)
           + fmaxf(a1.z - al[j][6], 0.f) + fmaxf(a1.w - al[j][7], 0.f);
  }

  float al2[4][8] = {};
  for (int q = 0; q < 64; q++) {
    float p0 = SP2[q * 65 + qg + 0];
    float p1 = SP2[q * 65 + qg + 1];
    float p2 = SP2[q * 65 + qg + 2];
    float p3 = SP2[q * 65 + qg + 3];
    float4 s0 = *(const float4*)(sq + q * 128 + dg);
    float4 s1 = *(const float4*)(sq + q * 128 + dg + 4);
    al2[0][0] += p0 * s0.x; al2[0][1] += p0 * s0.y; al2[0][2] += p0 * s0.z; al2[0][3] += p0 * s0.w;
    al2[0][4] += p0 * s1.x; al2[0][5] += p0 * s1.y; al2[0][6] += p0 * s1.z; al2[0][7] += p0 * s1.w;
    al2[1][0] += p1 * s0.x; al2[1][1] += p1 * s0.y; al2[1][2] += p1 * s0.z; al2[1][3] += p1 * s0.w;
    al2[1][4] += p1 * s1.x; al2[1][5] += p1 * s1.y; al2[1][6] += p1 * s1.z; al2[1][7] += p1 * s1.w;
    al2[2][0] += p2 * s0.x; al2[2][1] += p2 * s0.y; al2[2][2] += p2 * s0.z; al2[2][3] += p2 * s0.w;
    al2[2][4] += p2 * s1.x; al2[2][5] += p2 * s1.y; al2[2][6] += p2 * s1.z; al2[2][7] += p2 * s1.w;
    al2[3][0] += p3 * s0.x; al2[3][1] += p3 * s0.y; al2[3][2] += p3 * s0.z; al2[3][3] += p3 * s0.w;
    al2[3][4] += p3 * s1.x; al2[3][5] += p3 * s1.y; al2[3][6] += p3 * s1.z; al2[3][7] += p3 * s1.w;
  }
  float cpart = 0.f;
  #pragma unroll
  for (int j = 0; j < 4; j++) {
    float4 b0 = *(const float4*)(sc + (qg + j) * 128 + dg);
    float4 b1 = *(const float4*)(sc + (qg + j) * 128 + dg + 4);
    cpart += fmaxf(b0.x - al2[j][0], 0.f) + fmaxf(b0.y - al2[j][1], 0.f)
           + fmaxf(b0.z - al2[j][2], 0.f) + fmaxf(b0.w - al2[j][3], 0.f)
           + fmaxf(b1.x - al2[j][4], 0.f) + fmaxf(b1.y - al2[j][5], 0.f)
           + fmaxf(b1.z - al2[j][6], 0.f) + fmaxf(b1.w - al2[j][7], 0.f);
  }

  for (int off = 32; off > 0; off >>= 1) {
    qpart += __shfl_down(qpart, off);
    cpart += __shfl_down(cpart, off);
  }
  int wv = t >> 6;
  if ((t & 63) == 0) { red[wv] = qpart; red[wv + 4] = cpart; }
  __syncthreads();
  if (t == 0) {
    float qsum = red[0] + red[1] + red[2] + red[3];
    float csum = red[4] + red[5] + red[6] + red[7];
    out[b] = fminf(-qsum, -csum);
  }
}

// ---------------- launch ----------------
extern "C" void kernel_launch(void* const* d_in, const int* in_sizes, int n_in,
                              void* d_out, int out_size, void* d_ws, size_t ws_size,
                              hipStream_t stream)
{
  const float* nf  = (const float*)d_in[0];
  const float* ef  = (const float*)d_in[1];
  const int* from_idx = (const int*)d_in[2];
  const int* to_idx   = (const int*)d_in[3];
  const int* pos      = (const int*)d_in[4];
  const int* qsz      = (const int*)d_in[5];
  const int* csz      = (const int*)d_in[6];
  const float* W_node = (const float*)d_in[7];
  const float* b_node = (const float*)d_in[8];
  const float* W_edge = (const float*)d_in[9];
  const float* b_edge = (const float*)d_in[10];
  const float* W1 = (const float*)d_in[11];
  const float* b1 = (const float*)d_in[12];
  const float* W2 = (const float*)d_in[13];
  const float* b2 = (const float*)d_in[14];
  const float* Wu = (const float*)d_in[15];
  const float* bu = (const float*)d_in[16];
  const float* Wa1 = (const float*)d_in[17];
  const float* ba1 = (const float*)d_in[18];
  const float* Wa2 = (const float*)d_in[19];
  const float* ba2 = (const float*)d_in[20];
  float* out = (float*)d_out;

  int N = in_sizes[0] / NODE_F;
  int E = in_sizes[1] / EDGE_F;

  float* h    = (float*)d_ws;
  float* agg  = h + (size_t)N * D;
  float* flat = agg + (size_t)N * 256;
  float* tfb  = flat + (size_t)2 * B_PAIRS * MAXN * D;
  short* hb   = (short*)(tfb + (size_t)2 * B_PAIRS * MAXN * D);
  short* eb   = hb + (size_t)N * D;
  short* W1p  = eb + (size_t)E * EDIM;
  short* W2p  = W1p + 102400;
  short* Wup  = W2p + 81920;

  hipMemsetAsync(flat, 0, (size_t)2 * B_PAIRS * MAXN * D * sizeof(float), stream);

  prep_w<<<960, 256, 0, stream>>>(W1, W2, Wu, W1p, W2p, Wup);
  encode_nodes<<<(N + 1) / 2, 256, 0, stream>>>(nf, W_node, b_node, h, hb, N);
  encode_edges<<<(E + 3) / 4, 256, 0, stream>>>(ef, W_edge, b_edge, eb, E);

  for (int s = 0; s < PROP_STEPS; s++) {
    hipMemsetAsync(agg, 0, (size_t)N * 256 * sizeof(float), stream);
    msg_mfma<<<(E + 63) / 64, 256, 0, stream>>>(hb, eb, from_idx, to_idx,
                                                W1p, b1, W2p, b2, agg, E);
    update_mfma<<<(N + 31) / 32, 256, 0, stream>>>(h, hb, agg, Wup, bu, N);
  }

  scatter_kernel<<<(N * D + 255) / 256, 256, 0, stream>>>(h, pos, flat, N);
  attfeat_kernel<<<(2 * B_PAIRS * MAXN) / MTA, 256, 0, stream>>>(flat, Wa1, ba1, Wa2, ba2,
                                                                 qsz, csz, tfb);
  score_kernel<<<B_PAIRS, 256, 0, stream>>>(tfb, flat, qsz, csz, out);
}